// Round 1
// baseline (508.961 us; speedup 1.0000x reference)
//
#include <hip/hip_runtime.h>
#include <hip/hip_bf16.h>

#define D_DIM 256
#define K_CODES 1024
#define HW 1024
#define N_VEC 32768
#define N_ELEM 8388608ull

typedef __attribute__((ext_vector_type(8))) short bf16x8;
typedef __attribute__((ext_vector_type(4))) float f32x4;

static __device__ __forceinline__ unsigned short f2bf(float x) {
    union { __hip_bfloat16 h; unsigned short u; } cvt;
    cvt.h = __float2bfloat16(x);
    return cvt.u;
}

// ---------------------------------------------------------------------------
// Kernel A: codebook squared norms (fp32, exact)
// ---------------------------------------------------------------------------
__global__ __launch_bounds__(256) void cnorm_kernel(const float* __restrict__ cb,
                                                    float* __restrict__ cnorm) {
    int k = blockIdx.x * 256 + threadIdx.x;
    const float4* row = (const float4*)(cb + (size_t)k * D_DIM);
    float s = 0.f;
#pragma unroll 8
    for (int i = 0; i < D_DIM / 4; i++) {
        float4 v = row[i];
        s = fmaf(v.x, v.x, s);
        s = fmaf(v.y, v.y, s);
        s = fmaf(v.z, v.z, s);
        s = fmaf(v.w, v.w, s);
    }
    cnorm[k] = s;
}

// ---------------------------------------------------------------------------
// Kernel B: argmin over codes via bf16 MFMA (16x16x32).
// Block = 256 thr (4 waves), covers 64 n (vectors). Waves split k-range.
// score = ||c||^2 - 2*z.c  (dropping per-n ||z||^2 which doesn't move argmin).
// LDS holds A/B tiles in MFMA *fragment order* so frag loads are
// lane-contiguous b128 (conflict-free by construction).
// ---------------------------------------------------------------------------
__global__ __launch_bounds__(256) void argmin_mfma(const float* __restrict__ z,
                                                   const float* __restrict__ cb,
                                                   const float* __restrict__ cnorm,
                                                   int* __restrict__ indices,
                                                   int* __restrict__ counts) {
    // A: [4 s][2 c][64 lanes][8 bf16] = 8KB ; B: [16 sk][2 c][64][8] = 32KB
    __shared__ unsigned short Afrag[4 * 2 * 64 * 8];
    __shared__ unsigned short Bfrag[16 * 2 * 64 * 8];

    const int t = threadIdx.x;
    const int lane = t & 63;
    const int w = t >> 6;  // wave 0..3
    const int n0 = blockIdx.x * 64;
    const int b = n0 >> 10;
    const int hw0 = n0 & (HW - 1);
    const float* zbase = z + (size_t)b * (D_DIM * HW) + hw0;

    float bestd[4][4];
    int bestk[4][4];
#pragma unroll
    for (int s = 0; s < 4; s++)
#pragma unroll
        for (int r = 0; r < 4; r++) { bestd[s][r] = 3.4e38f; bestk[s][r] = 0; }

    for (int kc = 0; kc < 4; kc++) {
        const int k0 = kc * 256;
        f32x4 acc[4][4];
#pragma unroll
        for (int s = 0; s < 4; s++)
#pragma unroll
            for (int kt = 0; kt < 4; kt++) acc[s][kt] = (f32x4){0.f, 0.f, 0.f, 0.f};

        for (int st = 0; st < 4; st++) {
            const int d0 = st * 64;
            __syncthreads();
            // ---- stage A: 64 n x 64 d (z is NCHW: n contiguous, d strided) ----
#pragma unroll
            for (int p = 0; p < 4; p++) {
                int f = t + p * 256;          // 0..1023
                int d_idx = f >> 4;           // 0..63
                int nf = f & 15;              // float4 group along n
                float4 v = *(const float4*)(zbase + (size_t)(d0 + d_idx) * HW + nf * 4);
                int c = d_idx >> 5;
                int quad = (d_idx >> 3) & 3;
                int j = d_idx & 7;
                int nl = nf * 4;
                int s = nl >> 4;
                int row = nl & 15;
                int base = (((s * 2 + c) * 64) + quad * 16 + row) * 8 + j;
                Afrag[base]      = f2bf(v.x);
                Afrag[base + 8]  = f2bf(v.y);
                Afrag[base + 16] = f2bf(v.z);
                Afrag[base + 24] = f2bf(v.w);
            }
            // ---- stage B: 256 k x 64 d (cb row-major: d contiguous) ----
#pragma unroll
            for (int p = 0; p < 16; p++) {
                int f = t + p * 256;          // 0..4095
                int kk = f >> 4;              // 0..255
                int dd4 = (f & 15) * 4;       // 0..60
                float4 v = *(const float4*)(cb + (size_t)(k0 + kk) * D_DIM + d0 + dd4);
                int c = dd4 >> 5;
                int quad = (dd4 >> 3) & 3;
                int j0 = dd4 & 7;             // 0 or 4
                int sk = kk >> 4;
                int rowk = kk & 15;
                int base = (((sk * 2 + c) * 64) + quad * 16 + rowk) * 8 + j0;
                ushort4 pk;
                pk.x = f2bf(v.x); pk.y = f2bf(v.y); pk.z = f2bf(v.z); pk.w = f2bf(v.w);
                *(ushort4*)&Bfrag[base] = pk;
            }
            __syncthreads();
            // ---- compute: 2 d-chunks of 32 ----
#pragma unroll
            for (int c = 0; c < 2; c++) {
                bf16x8 a[4], bb[4];
#pragma unroll
                for (int s = 0; s < 4; s++)
                    a[s] = *(const bf16x8*)&Afrag[(((s * 2 + c) * 64) + lane) * 8];
#pragma unroll
                for (int kt = 0; kt < 4; kt++) {
                    int sk = w * 4 + kt;
                    bb[kt] = *(const bf16x8*)&Bfrag[(((sk * 2 + c) * 64) + lane) * 8];
                }
#pragma unroll
                for (int s = 0; s < 4; s++)
#pragma unroll
                    for (int kt = 0; kt < 4; kt++)
                        acc[s][kt] = __builtin_amdgcn_mfma_f32_16x16x32_bf16(
                            a[s], bb[kt], acc[s][kt], 0, 0, 0);
            }
        }
        // ---- epilogue: scores, running best (k ascending => first-min tiebreak) ----
        const int col = lane & 15;
#pragma unroll
        for (int kt = 0; kt < 4; kt++) {
            int k = k0 + w * 64 + kt * 16 + col;
            float cn = cnorm[k];
#pragma unroll
            for (int s = 0; s < 4; s++)
#pragma unroll
                for (int r = 0; r < 4; r++) {
                    float sc = fmaf(-2.0f, acc[s][kt][r], cn);
                    if (sc < bestd[s][r]) { bestd[s][r] = sc; bestk[s][r] = k; }
                }
        }
    }

    // ---- reduce across 16 lanes (same quad share an n), then across waves ----
    __syncthreads();  // done reading frag LDS; alias it for reduction
    float* redd = (float*)Afrag;  // [64 n][4 w]
    int* redk = (int*)Bfrag;      // [64 n][4 w]
#pragma unroll
    for (int s = 0; s < 4; s++)
#pragma unroll
        for (int r = 0; r < 4; r++) {
            float dd = bestd[s][r];
            int kk = bestk[s][r];
#pragma unroll
            for (int off = 8; off >= 1; off >>= 1) {
                float d2 = __shfl_xor(dd, off);
                int k2 = __shfl_xor(kk, off);
                if (d2 < dd || (d2 == dd && k2 < kk)) { dd = d2; kk = k2; }
            }
            if ((lane & 15) == 0) {
                int nl = s * 16 + (lane >> 4) * 4 + r;
                redd[nl * 4 + w] = dd;
                redk[nl * 4 + w] = kk;
            }
        }
    __syncthreads();
    if (t < 64) {
        float dd = redd[t * 4 + 0];
        int kk = redk[t * 4 + 0];
#pragma unroll
        for (int w2 = 1; w2 < 4; w2++) {
            float d2 = redd[t * 4 + w2];
            int k2 = redk[t * 4 + w2];
            if (d2 < dd || (d2 == dd && k2 < kk)) { dd = d2; kk = k2; }
        }
        indices[n0 + t] = kk;
        atomicAdd(&counts[kk], 1);
    }
}

// ---------------------------------------------------------------------------
// Kernel C: quantized output (STE: z + (q - z), fp32 like ref) + loss partial
// ---------------------------------------------------------------------------
__global__ __launch_bounds__(256) void quantize_loss(const float* __restrict__ z,
                                                     const float* __restrict__ cb,
                                                     const int* __restrict__ indices,
                                                     float* __restrict__ out,
                                                     float* __restrict__ lossacc) {
    int tid = blockIdx.x * 256 + threadIdx.x;  // 0..2097151
    size_t o = (size_t)tid * 4;
    int hw = (int)(o & (HW - 1));
    int d = (int)((o >> 10) & (D_DIM - 1));
    int b = (int)(o >> 18);
    int n = b * HW + hw;
    int4 idx = *(const int4*)(indices + n);
    float4 zv = *(const float4*)(z + o);
    float q0 = cb[(size_t)idx.x * D_DIM + d];
    float q1 = cb[(size_t)idx.y * D_DIM + d];
    float q2 = cb[(size_t)idx.z * D_DIM + d];
    float q3 = cb[(size_t)idx.w * D_DIM + d];
    float e0 = q0 - zv.x, e1 = q1 - zv.y, e2 = q2 - zv.z, e3 = q3 - zv.w;
    float4 ov;
    ov.x = zv.x + e0; ov.y = zv.y + e1; ov.z = zv.z + e2; ov.w = zv.w + e3;
    *(float4*)(out + o) = ov;
    float ls = e0 * e0 + e1 * e1 + e2 * e2 + e3 * e3;
#pragma unroll
    for (int off = 32; off >= 1; off >>= 1) ls += __shfl_down(ls, off);
    __shared__ float wsum[4];
    if ((threadIdx.x & 63) == 0) wsum[threadIdx.x >> 6] = ls;
    __syncthreads();
    if (threadIdx.x == 0) atomicAdd(lossacc, wsum[0] + wsum[1] + wsum[2] + wsum[3]);
}

// ---------------------------------------------------------------------------
// Kernel D: scatter ones into (pre-zeroed) encodings
// ---------------------------------------------------------------------------
__global__ __launch_bounds__(256) void scatter_ones(const int* __restrict__ indices,
                                                    float* __restrict__ enc) {
    int n = blockIdx.x * 256 + threadIdx.x;
    enc[(size_t)n * K_CODES + indices[n]] = 1.0f;
}

// ---------------------------------------------------------------------------
// Kernel E: finalize loss + perplexity
// ---------------------------------------------------------------------------
__global__ __launch_bounds__(256) void finalize_kernel(const int* __restrict__ counts,
                                                       const float* __restrict__ lossacc,
                                                       float* __restrict__ out_scalars) {
    int t = threadIdx.x;
    float s = 0.f;
#pragma unroll
    for (int i = 0; i < 4; i++) {
        int k = t + i * 256;
        float p = (float)counts[k] * (1.0f / 32768.0f);
        s += p * logf(p + 1e-10f);
    }
#pragma unroll
    for (int off = 32; off >= 1; off >>= 1) s += __shfl_down(s, off);
    __shared__ float red[4];
    if ((t & 63) == 0) red[t >> 6] = s;
    __syncthreads();
    if (t == 0) {
        float tot = red[0] + red[1] + red[2] + red[3];
        out_scalars[0] = 1.25f * (lossacc[0] * (1.0f / 8388608.0f));  // q + beta*e
        out_scalars[1] = expf(-tot);                                  // perplexity
    }
}

// ---------------------------------------------------------------------------
extern "C" void kernel_launch(void* const* d_in, const int* in_sizes, int n_in,
                              void* d_out, int out_size, void* d_ws, size_t ws_size,
                              hipStream_t stream) {
    const float* z = (const float*)d_in[0];   // [32,256,32,32]
    const float* cb = (const float*)d_in[1];  // [1024,256]
    float* out = (float*)d_out;
    char* wsb = (char*)d_ws;

    float* cnorm = (float*)wsb;             // 1024 f32
    int* counts = (int*)(wsb + 4096);       // 1024 i32
    float* lossacc = (float*)(wsb + 8192);  // 1 f32
    int* indices = (int*)(wsb + 16384);     // 32768 i32

    float* quant = out;                  // [0, 8388608)
    float* scal = out + N_ELEM;          // loss @ +0, perplexity @ +1
    float* enc = out + N_ELEM + 2;       // [8388610, +33554432)

    // zero counts + loss accumulator; zero one-hot encodings region
    hipMemsetAsync(counts, 0, 4100, stream);
    hipMemsetAsync(enc, 0, (size_t)N_VEC * K_CODES * sizeof(float), stream);

    hipLaunchKernelGGL(cnorm_kernel, dim3(4), dim3(256), 0, stream, cb, cnorm);
    hipLaunchKernelGGL(argmin_mfma, dim3(512), dim3(256), 0, stream, z, cb, cnorm,
                       indices, counts);
    hipLaunchKernelGGL(quantize_loss, dim3(8192), dim3(256), 0, stream, z, cb,
                       indices, quant, lossacc);
    hipLaunchKernelGGL(scatter_ones, dim3(128), dim3(256), 0, stream, indices, enc);
    hipLaunchKernelGGL(finalize_kernel, dim3(1), dim3(256), 0, stream, counts,
                       lossacc, scal);
}

// Round 2
// 409.442 us; speedup vs baseline: 1.2431x; 1.2431x over previous
//
#include <hip/hip_runtime.h>
#include <hip/hip_bf16.h>

#define D_DIM 256
#define K_CODES 1024
#define HW 1024
#define N_VEC 32768
#define N_ELEM 8388608ull

typedef __attribute__((ext_vector_type(8))) short bf16x8;
typedef __attribute__((ext_vector_type(4))) float f32x4;

static __device__ __forceinline__ unsigned short f2bf(float x) {
    union { __hip_bfloat16 h; unsigned short u; } cvt;
    cvt.h = __float2bfloat16(x);
    return cvt.u;
}

// ---------------------------------------------------------------------------
// Kernel A: codebook squared norms (fp32, exact)
// ---------------------------------------------------------------------------
__global__ __launch_bounds__(256) void cnorm_kernel(const float* __restrict__ cb,
                                                    float* __restrict__ cnorm) {
    int k = blockIdx.x * 256 + threadIdx.x;
    const float4* row = (const float4*)(cb + (size_t)k * D_DIM);
    float s = 0.f;
#pragma unroll 8
    for (int i = 0; i < D_DIM / 4; i++) {
        float4 v = row[i];
        s = fmaf(v.x, v.x, s);
        s = fmaf(v.y, v.y, s);
        s = fmaf(v.z, v.z, s);
        s = fmaf(v.w, v.w, s);
    }
    cnorm[k] = s;
}

// ---------------------------------------------------------------------------
// Kernel B1: codebook -> bf16 in MFMA B-fragment order.
// Slot (ktile, dchunk): lane l holds cb[ktile*16 + (l&15)][dchunk*32 + (l>>4)*8 + j]
// ---------------------------------------------------------------------------
__global__ __launch_bounds__(256) void cbprep_kernel(const float* __restrict__ cb,
                                                     unsigned short* __restrict__ cbb) {
    int slot = blockIdx.x * 256 + threadIdx.x;  // 0 .. 64*8*64-1 = 32767
    int lane = slot & 63;
    int dchunk = (slot >> 6) & 7;
    int ktile = slot >> 9;
    int code = ktile * 16 + (lane & 15);
    int d0 = dchunk * 32 + (lane >> 4) * 8;
    const float4* src = (const float4*)(cb + (size_t)code * D_DIM + d0);
    float4 v0 = src[0], v1 = src[1];
    int4 o;
    o.x = f2bf(v0.x) | ((unsigned)f2bf(v0.y) << 16);
    o.y = f2bf(v0.z) | ((unsigned)f2bf(v0.w) << 16);
    o.z = f2bf(v1.x) | ((unsigned)f2bf(v1.y) << 16);
    o.w = f2bf(v1.z) | ((unsigned)f2bf(v1.w) << 16);
    *(int4*)(cbb + (size_t)slot * 8) = o;
}

// ---------------------------------------------------------------------------
// Kernel B2: z (NCHW fp32) -> bf16 in MFMA A-fragment order.
// Slot (ntile, dchunk): lane l holds z_flat[ntile*16 + (l&15)][dchunk*32 + (l>>4)*8 + j]
// where z_flat[n][d] = z[n>>10][d][n&1023].
// ---------------------------------------------------------------------------
__global__ __launch_bounds__(256) void zprep_kernel(const float* __restrict__ z,
                                                    unsigned short* __restrict__ zb) {
    int slot = blockIdx.x * 256 + threadIdx.x;  // 0 .. 2048*8*64-1
    int lane = slot & 63;
    int dchunk = (slot >> 6) & 7;
    int ntile = slot >> 9;
    int n = ntile * 16 + (lane & 15);
    int b = n >> 10;
    int hw = n & (HW - 1);
    int d0 = dchunk * 32 + (lane >> 4) * 8;
    const float* src = z + (((size_t)(b * D_DIM + d0)) << 10) + hw;
    unsigned short u[8];
#pragma unroll
    for (int j = 0; j < 8; j++) u[j] = f2bf(src[(size_t)j << 10]);
    int4 o;
    o.x = u[0] | ((unsigned)u[1] << 16);
    o.y = u[2] | ((unsigned)u[3] << 16);
    o.z = u[4] | ((unsigned)u[5] << 16);
    o.w = u[6] | ((unsigned)u[7] << 16);
    *(int4*)(zb + (size_t)slot * 8) = o;
}

// ---------------------------------------------------------------------------
// Kernel C: argmin over codes via bf16 MFMA, fragment-direct global loads.
// Block = 512 thr (8 waves). Wave w owns 16 n (one ntile); all waves share the
// same B addresses (L1 broadcast). No LDS, no staging, no conversion.
// score = ||c||^2 - 2*z.c  (per-n ||z||^2 dropped; doesn't move argmin).
// ---------------------------------------------------------------------------
__global__ __launch_bounds__(512, 2) void argmin_mfma(const unsigned short* __restrict__ zb,
                                                      const unsigned short* __restrict__ cbb,
                                                      const float* __restrict__ cnorm,
                                                      int* __restrict__ indices,
                                                      int* __restrict__ counts) {
    const int t = threadIdx.x;
    const int lane = t & 63;
    const int w = t >> 6;  // wave 0..7
    const int ntile = blockIdx.x * 8 + w;
    const bf16x8* Z = (const bf16x8*)zb;
    const bf16x8* C = (const bf16x8*)cbb;

    // A fragments for this wave's 16 n, all of D: 8 frags = 32 VGPRs
    bf16x8 Ar[8];
#pragma unroll
    for (int dc = 0; dc < 8; dc++)
        Ar[dc] = Z[((size_t)ntile * 8 + dc) * 64 + lane];

    float bestd[4];
    int bestk[4];
#pragma unroll
    for (int r = 0; r < 4; r++) { bestd[r] = 3.4e38f; bestk[r] = 0; }

    for (int kc = 0; kc < 4; kc++) {
        __syncthreads();  // keep waves loosely in step for L1 B-sharing
        f32x4 acc[16];
#pragma unroll
        for (int kt = 0; kt < 16; kt++) acc[kt] = (f32x4){0.f, 0.f, 0.f, 0.f};
#pragma unroll
        for (int dc = 0; dc < 8; dc++) {
            bf16x8 bb[16];
#pragma unroll
            for (int kt = 0; kt < 16; kt++)
                bb[kt] = C[((size_t)(kc * 16 + kt) * 8 + dc) * 64 + lane];
#pragma unroll
            for (int kt = 0; kt < 16; kt++)
                acc[kt] = __builtin_amdgcn_mfma_f32_16x16x32_bf16(Ar[dc], bb[kt],
                                                                  acc[kt], 0, 0, 0);
        }
        // epilogue: running best (k ascending => first-min tiebreak)
        const int col = lane & 15;
#pragma unroll
        for (int kt = 0; kt < 16; kt++) {
            int k = kc * 256 + kt * 16 + col;
            float cn = cnorm[k];
#pragma unroll
            for (int r = 0; r < 4; r++) {
                float sc = fmaf(-2.0f, acc[kt][r], cn);
                if (sc < bestd[r]) { bestd[r] = sc; bestk[r] = k; }
            }
        }
    }

    // reduce across the 16 columns (lanes with same lane>>4 hold same n)
#pragma unroll
    for (int r = 0; r < 4; r++) {
        float dd = bestd[r];
        int kk = bestk[r];
#pragma unroll
        for (int off = 8; off >= 1; off >>= 1) {
            float d2 = __shfl_xor(dd, off);
            int k2 = __shfl_xor(kk, off);
            if (d2 < dd || (d2 == dd && k2 < kk)) { dd = d2; kk = k2; }
        }
        if ((lane & 15) == 0) {
            int n = ntile * 16 + (lane >> 4) * 4 + r;
            indices[n] = kk;
            atomicAdd(&counts[kk], 1);
        }
    }
}

// ---------------------------------------------------------------------------
// Kernel D: quantized output (STE: z + (q - z), fp32 like ref) + loss partial
// ---------------------------------------------------------------------------
__global__ __launch_bounds__(256) void quantize_loss(const float* __restrict__ z,
                                                     const float* __restrict__ cb,
                                                     const int* __restrict__ indices,
                                                     float* __restrict__ out,
                                                     float* __restrict__ lossacc) {
    int tid = blockIdx.x * 256 + threadIdx.x;  // 0..2097151
    size_t o = (size_t)tid * 4;
    int hw = (int)(o & (HW - 1));
    int d = (int)((o >> 10) & (D_DIM - 1));
    int b = (int)(o >> 18);
    int n = b * HW + hw;
    int4 idx = *(const int4*)(indices + n);
    float4 zv = *(const float4*)(z + o);
    float q0 = cb[(size_t)idx.x * D_DIM + d];
    float q1 = cb[(size_t)idx.y * D_DIM + d];
    float q2 = cb[(size_t)idx.z * D_DIM + d];
    float q3 = cb[(size_t)idx.w * D_DIM + d];
    float e0 = q0 - zv.x, e1 = q1 - zv.y, e2 = q2 - zv.z, e3 = q3 - zv.w;
    float4 ov;
    ov.x = zv.x + e0; ov.y = zv.y + e1; ov.z = zv.z + e2; ov.w = zv.w + e3;
    *(float4*)(out + o) = ov;
    float ls = e0 * e0 + e1 * e1 + e2 * e2 + e3 * e3;
#pragma unroll
    for (int off = 32; off >= 1; off >>= 1) ls += __shfl_down(ls, off);
    __shared__ float wsum[4];
    if ((threadIdx.x & 63) == 0) wsum[threadIdx.x >> 6] = ls;
    __syncthreads();
    if (threadIdx.x == 0) atomicAdd(lossacc, wsum[0] + wsum[1] + wsum[2] + wsum[3]);
}

// ---------------------------------------------------------------------------
// Kernel E: write one-hot encodings (fused zero + scatter; 8B-aligned stores)
// ---------------------------------------------------------------------------
__global__ __launch_bounds__(256) void write_encodings(const int* __restrict__ indices,
                                                       float* __restrict__ enc) {
    int gid = blockIdx.x * 256 + threadIdx.x;  // 0..8388607, 4 floats each
    int n = gid >> 8;
    int k0 = (gid & 255) << 2;
    int idx = indices[n];
    float2 a, b2;
    a.x = (k0 == idx) ? 1.f : 0.f;
    a.y = (k0 + 1 == idx) ? 1.f : 0.f;
    b2.x = (k0 + 2 == idx) ? 1.f : 0.f;
    b2.y = (k0 + 3 == idx) ? 1.f : 0.f;
    float* p = enc + (size_t)gid * 4;
    *(float2*)p = a;
    *(float2*)(p + 2) = b2;
}

// ---------------------------------------------------------------------------
// Kernel F: finalize loss + perplexity
// ---------------------------------------------------------------------------
__global__ __launch_bounds__(256) void finalize_kernel(const int* __restrict__ counts,
                                                       const float* __restrict__ lossacc,
                                                       float* __restrict__ out_scalars) {
    int t = threadIdx.x;
    float s = 0.f;
#pragma unroll
    for (int i = 0; i < 4; i++) {
        int k = t + i * 256;
        float p = (float)counts[k] * (1.0f / 32768.0f);
        s += p * logf(p + 1e-10f);
    }
#pragma unroll
    for (int off = 32; off >= 1; off >>= 1) s += __shfl_down(s, off);
    __shared__ float red[4];
    if ((t & 63) == 0) red[t >> 6] = s;
    __syncthreads();
    if (t == 0) {
        float tot = red[0] + red[1] + red[2] + red[3];
        out_scalars[0] = 1.25f * (lossacc[0] * (1.0f / 8388608.0f));  // q + beta*e
        out_scalars[1] = expf(-tot);                                  // perplexity
    }
}

// ---------------------------------------------------------------------------
extern "C" void kernel_launch(void* const* d_in, const int* in_sizes, int n_in,
                              void* d_out, int out_size, void* d_ws, size_t ws_size,
                              hipStream_t stream) {
    const float* z = (const float*)d_in[0];   // [32,256,32,32]
    const float* cb = (const float*)d_in[1];  // [1024,256]
    float* out = (float*)d_out;
    char* wsb = (char*)d_ws;

    float* cnorm = (float*)wsb;             // 1024 f32
    int* counts = (int*)(wsb + 4096);       // 1024 i32
    float* lossacc = (float*)(wsb + 8192);  // 1 f32
    int* indices = (int*)(wsb + 16384);     // 32768 i32

    float* quant = out;             // [0, 8388608)
    float* scal = out + N_ELEM;     // loss @ +0, perplexity @ +1
    float* enc = out + N_ELEM + 2;  // [8388610, +33554432)

    // zb (16MB) + cbb (512KB) live inside the encodings region of d_out;
    // they are fully consumed by argmin_mfma before write_encodings
    // overwrites the region (same-stream ordering). 16B-aligned offsets.
    unsigned short* zb = (unsigned short*)(out + 8388612);    // 2048*8*64*16B
    unsigned short* cbb = (unsigned short*)(out + 12582916);  // 64*8*64*16B

    hipMemsetAsync(counts, 0, 4100, stream);  // counts + lossacc

    hipLaunchKernelGGL(cnorm_kernel, dim3(4), dim3(256), 0, stream, cb, cnorm);
    hipLaunchKernelGGL(cbprep_kernel, dim3(128), dim3(256), 0, stream, cb, cbb);
    hipLaunchKernelGGL(zprep_kernel, dim3(4096), dim3(256), 0, stream, z, zb);
    hipLaunchKernelGGL(argmin_mfma, dim3(256), dim3(512), 0, stream, zb, cbb,
                       cnorm, indices, counts);
    hipLaunchKernelGGL(quantize_loss, dim3(8192), dim3(256), 0, stream, z, cb,
                       indices, quant, lossacc);
    hipLaunchKernelGGL(write_encodings, dim3(32768), dim3(256), 0, stream,
                       indices, enc);
    hipLaunchKernelGGL(finalize_kernel, dim3(1), dim3(256), 0, stream, counts,
                       lossacc, scal);
}

// Round 3
// 310.961 us; speedup vs baseline: 1.6367x; 1.3167x over previous
//
#include <hip/hip_runtime.h>
#include <hip/hip_bf16.h>

#define D_DIM 256
#define K_CODES 1024
#define HW 1024
#define N_VEC 32768
#define N_ELEM 8388608ull

typedef __attribute__((ext_vector_type(8))) short bf16x8;
typedef __attribute__((ext_vector_type(4))) float f32x4;

static __device__ __forceinline__ unsigned short f2bf(float x) {
    union { __hip_bfloat16 h; unsigned short u; } cvt;
    cvt.h = __float2bfloat16(x);
    return cvt.u;
}

// ---------------------------------------------------------------------------
// Kernel A: codebook squared norms (fp32, exact) + zero counts/lossacc.
// 8 lanes per code row; grid 32x256 = 8192 threads.
// ---------------------------------------------------------------------------
__global__ __launch_bounds__(256) void cnorm_kernel(const float* __restrict__ cb,
                                                    float* __restrict__ cnorm,
                                                    int* __restrict__ counts,
                                                    float* __restrict__ lossacc) {
    int g = blockIdx.x * 256 + threadIdx.x;  // 0..8191
    if (g < K_CODES) counts[g] = 0;
    if (g == K_CODES) lossacc[0] = 0.f;
    int k = g >> 3;
    int part = g & 7;
    const float4* row = (const float4*)(cb + (size_t)k * D_DIM + part * 32);
    float s = 0.f;
#pragma unroll
    for (int i = 0; i < 8; i++) {
        float4 v = row[i];
        s = fmaf(v.x, v.x, s);
        s = fmaf(v.y, v.y, s);
        s = fmaf(v.z, v.z, s);
        s = fmaf(v.w, v.w, s);
    }
    s += __shfl_xor(s, 1);
    s += __shfl_xor(s, 2);
    s += __shfl_xor(s, 4);
    if (part == 0) cnorm[k] = s;
}

// ---------------------------------------------------------------------------
// Kernel B1: codebook -> bf16 in MFMA B-fragment order.
// ---------------------------------------------------------------------------
__global__ __launch_bounds__(256) void cbprep_kernel(const float* __restrict__ cb,
                                                     unsigned short* __restrict__ cbb) {
    int slot = blockIdx.x * 256 + threadIdx.x;  // 0 .. 32767
    int lane = slot & 63;
    int dchunk = (slot >> 6) & 7;
    int ktile = slot >> 9;
    int code = ktile * 16 + (lane & 15);
    int d0 = dchunk * 32 + (lane >> 4) * 8;
    const float4* src = (const float4*)(cb + (size_t)code * D_DIM + d0);
    float4 v0 = src[0], v1 = src[1];
    int4 o;
    o.x = f2bf(v0.x) | ((unsigned)f2bf(v0.y) << 16);
    o.y = f2bf(v0.z) | ((unsigned)f2bf(v0.w) << 16);
    o.z = f2bf(v1.x) | ((unsigned)f2bf(v1.y) << 16);
    o.w = f2bf(v1.z) | ((unsigned)f2bf(v1.w) << 16);
    *(int4*)(cbb + (size_t)slot * 8) = o;
}

// ---------------------------------------------------------------------------
// Kernel B2: z (NCHW fp32) -> bf16 in MFMA A-fragment order.
// ---------------------------------------------------------------------------
__global__ __launch_bounds__(256) void zprep_kernel(const float* __restrict__ z,
                                                    unsigned short* __restrict__ zb) {
    int slot = blockIdx.x * 256 + threadIdx.x;  // 0 .. 2048*8*64-1
    int lane = slot & 63;
    int dchunk = (slot >> 6) & 7;
    int ntile = slot >> 9;
    int n = ntile * 16 + (lane & 15);
    int b = n >> 10;
    int hw = n & (HW - 1);
    int d0 = dchunk * 32 + (lane >> 4) * 8;
    const float* src = z + (((size_t)(b * D_DIM + d0)) << 10) + hw;
    unsigned short u[8];
#pragma unroll
    for (int j = 0; j < 8; j++) u[j] = f2bf(src[(size_t)j << 10]);
    int4 o;
    o.x = u[0] | ((unsigned)u[1] << 16);
    o.y = u[2] | ((unsigned)u[3] << 16);
    o.z = u[4] | ((unsigned)u[5] << 16);
    o.w = u[6] | ((unsigned)u[7] << 16);
    *(int4*)(zb + (size_t)slot * 8) = o;
}

// ---------------------------------------------------------------------------
// Kernel C: argmin over codes via bf16 MFMA, fragment-direct global loads.
// ---------------------------------------------------------------------------
__global__ __launch_bounds__(512, 2) void argmin_mfma(const unsigned short* __restrict__ zb,
                                                      const unsigned short* __restrict__ cbb,
                                                      const float* __restrict__ cnorm,
                                                      int* __restrict__ indices,
                                                      int* __restrict__ counts) {
    const int t = threadIdx.x;
    const int lane = t & 63;
    const int w = t >> 6;  // wave 0..7
    const int ntile = blockIdx.x * 8 + w;
    const bf16x8* Z = (const bf16x8*)zb;
    const bf16x8* C = (const bf16x8*)cbb;

    bf16x8 Ar[8];
#pragma unroll
    for (int dc = 0; dc < 8; dc++)
        Ar[dc] = Z[((size_t)ntile * 8 + dc) * 64 + lane];

    float bestd[4];
    int bestk[4];
#pragma unroll
    for (int r = 0; r < 4; r++) { bestd[r] = 3.4e38f; bestk[r] = 0; }

    for (int kc = 0; kc < 4; kc++) {
        __syncthreads();
        f32x4 acc[16];
#pragma unroll
        for (int kt = 0; kt < 16; kt++) acc[kt] = (f32x4){0.f, 0.f, 0.f, 0.f};
#pragma unroll
        for (int dc = 0; dc < 8; dc++) {
            bf16x8 bb[16];
#pragma unroll
            for (int kt = 0; kt < 16; kt++)
                bb[kt] = C[((size_t)(kc * 16 + kt) * 8 + dc) * 64 + lane];
#pragma unroll
            for (int kt = 0; kt < 16; kt++)
                acc[kt] = __builtin_amdgcn_mfma_f32_16x16x32_bf16(Ar[dc], bb[kt],
                                                                  acc[kt], 0, 0, 0);
        }
        const int col = lane & 15;
#pragma unroll
        for (int kt = 0; kt < 16; kt++) {
            int k = kc * 256 + kt * 16 + col;
            float cn = cnorm[k];
#pragma unroll
            for (int r = 0; r < 4; r++) {
                float sc = fmaf(-2.0f, acc[kt][r], cn);
                if (sc < bestd[r]) { bestd[r] = sc; bestk[r] = k; }
            }
        }
    }

#pragma unroll
    for (int r = 0; r < 4; r++) {
        float dd = bestd[r];
        int kk = bestk[r];
#pragma unroll
        for (int off = 8; off >= 1; off >>= 1) {
            float d2 = __shfl_xor(dd, off);
            int k2 = __shfl_xor(kk, off);
            if (d2 < dd || (d2 == dd && k2 < kk)) { dd = d2; kk = k2; }
        }
        if ((lane & 15) == 0) {
            int n = ntile * 16 + (lane >> 4) * 4 + r;
            indices[n] = kk;
            atomicAdd(&counts[kk], 1);
        }
    }
}

// ---------------------------------------------------------------------------
// Kernel D: quantize + STE output + loss, LDS-staged codebook rows.
// Block = 32 n (one b, 32 hw) x all 256 d. qs row stride 257 floats:
// staging-write banks (r + 4*f4 + j): 2 lanes/bank; read banks (h + d): 2/bank.
// ---------------------------------------------------------------------------
__global__ __launch_bounds__(256) void quantize_loss(const float* __restrict__ z,
                                                     const float* __restrict__ cb,
                                                     const int* __restrict__ indices,
                                                     float* __restrict__ out,
                                                     float* __restrict__ lossacc) {
    __shared__ float qs[32 * 257];
    __shared__ float wsum[4];
    const int t = threadIdx.x;
    const int lane = t & 63;
    const int w = t >> 6;
    const int n0 = blockIdx.x * 32;
    const int b = n0 >> 10;
    const int hw0 = n0 & (HW - 1);

    // ---- stage 32 codebook rows into LDS (coalesced global, conflict-free LDS)
    {
        const int rsub = lane >> 4;  // 0..3
        const int f4b = lane & 15;   // 0..15
#pragma unroll
        for (int j = 0; j < 2; j++) {
            int r = (w * 2 + j) * 4 + rsub;  // 0..31
            int code = indices[n0 + r];
            const float4* src = (const float4*)(cb + (size_t)code * D_DIM);
#pragma unroll
            for (int k = 0; k < 4; k++) {
                int f4 = f4b + 16 * k;  // 0..63
                float4 v = src[f4];
                float* dst = &qs[r * 257 + f4 * 4];
                dst[0] = v.x;
                dst[1] = v.y;
                dst[2] = v.z;
                dst[3] = v.w;
            }
        }
    }
    __syncthreads();

    // ---- compute: lane -> hw (coalesced), waves split d; 2 d per wave-inst
    const int h = lane & 31;
    const int dhalf = lane >> 5;  // 0 or 1
    float ls = 0.f;
#pragma unroll 4
    for (int i = 0; i < 32; i++) {
        int d = (i * 4 + w) * 2 + dhalf;  // 0..255
        size_t o = (((size_t)(b * D_DIM + d)) << 10) + hw0 + h;
        float q = qs[h * 257 + d];
        float zv = z[o];
        float e = q - zv;
        out[o] = zv + e;
        ls = fmaf(e, e, ls);
    }
#pragma unroll
    for (int off = 32; off >= 1; off >>= 1) ls += __shfl_down(ls, off);
    if (lane == 0) wsum[w] = ls;
    __syncthreads();
    if (t == 0) atomicAdd(lossacc, wsum[0] + wsum[1] + wsum[2] + wsum[3]);
}

// ---------------------------------------------------------------------------
// Kernel E: write one-hot encodings (fused zero + scatter; 8B-aligned stores)
// ---------------------------------------------------------------------------
__global__ __launch_bounds__(256) void write_encodings(const int* __restrict__ indices,
                                                       float* __restrict__ enc) {
    int gid = blockIdx.x * 256 + threadIdx.x;  // 0..8388607, 4 floats each
    int n = gid >> 8;
    int k0 = (gid & 255) << 2;
    int idx = indices[n];
    float2 a, b2;
    a.x = (k0 == idx) ? 1.f : 0.f;
    a.y = (k0 + 1 == idx) ? 1.f : 0.f;
    b2.x = (k0 + 2 == idx) ? 1.f : 0.f;
    b2.y = (k0 + 3 == idx) ? 1.f : 0.f;
    float* p = enc + (size_t)gid * 4;
    *(float2*)p = a;
    *(float2*)(p + 2) = b2;
}

// ---------------------------------------------------------------------------
// Kernel F: finalize loss + perplexity
// ---------------------------------------------------------------------------
__global__ __launch_bounds__(256) void finalize_kernel(const int* __restrict__ counts,
                                                       const float* __restrict__ lossacc,
                                                       float* __restrict__ out_scalars) {
    int t = threadIdx.x;
    float s = 0.f;
#pragma unroll
    for (int i = 0; i < 4; i++) {
        int k = t + i * 256;
        float p = (float)counts[k] * (1.0f / 32768.0f);
        s += p * logf(p + 1e-10f);
    }
#pragma unroll
    for (int off = 32; off >= 1; off >>= 1) s += __shfl_down(s, off);
    __shared__ float red[4];
    if ((t & 63) == 0) red[t >> 6] = s;
    __syncthreads();
    if (t == 0) {
        float tot = red[0] + red[1] + red[2] + red[3];
        out_scalars[0] = 1.25f * (lossacc[0] * (1.0f / 8388608.0f));  // q + beta*e
        out_scalars[1] = expf(-tot);                                  // perplexity
    }
}

// ---------------------------------------------------------------------------
extern "C" void kernel_launch(void* const* d_in, const int* in_sizes, int n_in,
                              void* d_out, int out_size, void* d_ws, size_t ws_size,
                              hipStream_t stream) {
    const float* z = (const float*)d_in[0];   // [32,256,32,32]
    const float* cb = (const float*)d_in[1];  // [1024,256]
    float* out = (float*)d_out;
    char* wsb = (char*)d_ws;

    float* cnorm = (float*)wsb;             // 1024 f32
    int* counts = (int*)(wsb + 4096);       // 1024 i32
    float* lossacc = (float*)(wsb + 8192);  // 1 f32
    int* indices = (int*)(wsb + 16384);     // 32768 i32

    float* quant = out;             // [0, 8388608)
    float* scal = out + N_ELEM;     // loss @ +0, perplexity @ +1
    float* enc = out + N_ELEM + 2;  // [8388610, +33554432)

    // zb (16MB) + cbb (512KB) live inside the encodings region of d_out;
    // fully consumed by argmin_mfma before write_encodings overwrites them.
    unsigned short* zb = (unsigned short*)(out + 8388612);    // 16B-aligned
    unsigned short* cbb = (unsigned short*)(out + 12582916);  // 16B-aligned

    hipLaunchKernelGGL(cnorm_kernel, dim3(32), dim3(256), 0, stream, cb, cnorm,
                       counts, lossacc);
    hipLaunchKernelGGL(cbprep_kernel, dim3(128), dim3(256), 0, stream, cb, cbb);
    hipLaunchKernelGGL(zprep_kernel, dim3(4096), dim3(256), 0, stream, z, zb);
    hipLaunchKernelGGL(argmin_mfma, dim3(256), dim3(512), 0, stream, zb, cbb,
                       cnorm, indices, counts);
    hipLaunchKernelGGL(quantize_loss, dim3(1024), dim3(256), 0, stream, z, cb,
                       indices, quant, lossacc);
    hipLaunchKernelGGL(write_encodings, dim3(32768), dim3(256), 0, stream,
                       indices, enc);
    hipLaunchKernelGGL(finalize_kernel, dim3(1), dim3(256), 0, stream, counts,
                       lossacc, scal);
}

// Round 4
// 288.303 us; speedup vs baseline: 1.7654x; 1.0786x over previous
//
#include <hip/hip_runtime.h>
#include <hip/hip_bf16.h>

#define D_DIM 256
#define K_CODES 1024
#define HW 1024
#define N_VEC 32768
#define N_ELEM 8388608ull

typedef __attribute__((ext_vector_type(8))) short bf16x8;
typedef __attribute__((ext_vector_type(4))) float f32x4;

static __device__ __forceinline__ unsigned short f2bf(float x) {
    union { __hip_bfloat16 h; unsigned short u; } cvt;
    cvt.h = __float2bfloat16(x);
    return cvt.u;
}

// ---------------------------------------------------------------------------
// Kernel A: codebook squared norms (fp32, exact) + zero counts/lossacc.
// ---------------------------------------------------------------------------
__global__ __launch_bounds__(256) void cnorm_kernel(const float* __restrict__ cb,
                                                    float* __restrict__ cnorm,
                                                    int* __restrict__ counts,
                                                    float* __restrict__ lossacc) {
    int g = blockIdx.x * 256 + threadIdx.x;  // 0..8191
    if (g < K_CODES) counts[g] = 0;
    if (g == K_CODES) lossacc[0] = 0.f;
    int k = g >> 3;
    int part = g & 7;
    const float4* row = (const float4*)(cb + (size_t)k * D_DIM + part * 32);
    float s = 0.f;
#pragma unroll
    for (int i = 0; i < 8; i++) {
        float4 v = row[i];
        s = fmaf(v.x, v.x, s);
        s = fmaf(v.y, v.y, s);
        s = fmaf(v.z, v.z, s);
        s = fmaf(v.w, v.w, s);
    }
    s += __shfl_xor(s, 1);
    s += __shfl_xor(s, 2);
    s += __shfl_xor(s, 4);
    if (part == 0) cnorm[k] = s;
}

// ---------------------------------------------------------------------------
// Kernel B1: codebook -> bf16 in MFMA B-fragment order.
// ---------------------------------------------------------------------------
__global__ __launch_bounds__(256) void cbprep_kernel(const float* __restrict__ cb,
                                                     unsigned short* __restrict__ cbb) {
    int slot = blockIdx.x * 256 + threadIdx.x;  // 0 .. 32767
    int lane = slot & 63;
    int dchunk = (slot >> 6) & 7;
    int ktile = slot >> 9;
    int code = ktile * 16 + (lane & 15);
    int d0 = dchunk * 32 + (lane >> 4) * 8;
    const float4* src = (const float4*)(cb + (size_t)code * D_DIM + d0);
    float4 v0 = src[0], v1 = src[1];
    int4 o;
    o.x = f2bf(v0.x) | ((unsigned)f2bf(v0.y) << 16);
    o.y = f2bf(v0.z) | ((unsigned)f2bf(v0.w) << 16);
    o.z = f2bf(v1.x) | ((unsigned)f2bf(v1.y) << 16);
    o.w = f2bf(v1.z) | ((unsigned)f2bf(v1.w) << 16);
    *(int4*)(cbb + (size_t)slot * 8) = o;
}

// ---------------------------------------------------------------------------
// Kernel B2: z (NCHW fp32) -> bf16 in MFMA A-fragment order.
// ---------------------------------------------------------------------------
__global__ __launch_bounds__(256) void zprep_kernel(const float* __restrict__ z,
                                                    unsigned short* __restrict__ zb) {
    int slot = blockIdx.x * 256 + threadIdx.x;  // 0 .. 2048*8*64-1
    int lane = slot & 63;
    int dchunk = (slot >> 6) & 7;
    int ntile = slot >> 9;
    int n = ntile * 16 + (lane & 15);
    int b = n >> 10;
    int hw = n & (HW - 1);
    int d0 = dchunk * 32 + (lane >> 4) * 8;
    const float* src = z + (((size_t)(b * D_DIM + d0)) << 10) + hw;
    unsigned short u[8];
#pragma unroll
    for (int j = 0; j < 8; j++) u[j] = f2bf(src[(size_t)j << 10]);
    int4 o;
    o.x = u[0] | ((unsigned)u[1] << 16);
    o.y = u[2] | ((unsigned)u[3] << 16);
    o.z = u[4] | ((unsigned)u[5] << 16);
    o.w = u[6] | ((unsigned)u[7] << 16);
    *(int4*)(zb + (size_t)slot * 8) = o;
}

// ---------------------------------------------------------------------------
// Kernel C: argmin via bf16 MFMA, split-K + 2-ntile B-amortization.
// Block = 512 thr (8 waves) covering 128 n. Wave w: ntile pair p = w&3
// (ntiles 2p,2p+1), K-half h = w>>2 (codes [512h, 512h+512)).
// Per dc-step: 8 B-frag loads feed 16 MFMAs (2 ntiles share each B frag).
// No barriers in the K loop; cross-half combine through 2KB LDS at the end.
// score = ||c||^2 - 2*z.c  (per-n ||z||^2 dropped; doesn't move argmin).
// ---------------------------------------------------------------------------
__global__ __launch_bounds__(512, 2) void argmin_mfma(const unsigned short* __restrict__ zb,
                                                      const unsigned short* __restrict__ cbb,
                                                      const float* __restrict__ cnorm,
                                                      int* __restrict__ indices,
                                                      int* __restrict__ counts) {
    __shared__ float sd[128][2];
    __shared__ int sk[128][2];
    const int t = threadIdx.x;
    const int lane = t & 63;
    const int w = t >> 6;  // 0..7
    const int p = w & 3;   // ntile pair within block
    const int h = w >> 2;  // K-half
    const int nt0 = blockIdx.x * 8 + p * 2;
    const bf16x8* Z = (const bf16x8*)zb;
    const bf16x8* C = (const bf16x8*)cbb;

    bf16x8 Ar[2][8];
#pragma unroll
    for (int nt = 0; nt < 2; nt++)
#pragma unroll
        for (int dc = 0; dc < 8; dc++)
            Ar[nt][dc] = Z[((size_t)(nt0 + nt) * 8 + dc) * 64 + lane];

    float bestd[2][4];
    int bestk[2][4];
#pragma unroll
    for (int nt = 0; nt < 2; nt++)
#pragma unroll
        for (int r = 0; r < 4; r++) { bestd[nt][r] = 3.4e38f; bestk[nt][r] = 0; }

    for (int kch = 0; kch < 4; kch++) {
        const int ktbase = h * 32 + kch * 8;
        f32x4 acc[2][8];
#pragma unroll
        for (int nt = 0; nt < 2; nt++)
#pragma unroll
            for (int kt = 0; kt < 8; kt++) acc[nt][kt] = (f32x4){0.f, 0.f, 0.f, 0.f};
#pragma unroll
        for (int dc = 0; dc < 8; dc++) {
            bf16x8 bb[8];
#pragma unroll
            for (int kt = 0; kt < 8; kt++)
                bb[kt] = C[((size_t)(ktbase + kt) * 8 + dc) * 64 + lane];
#pragma unroll
            for (int kt = 0; kt < 8; kt++)
                acc[0][kt] = __builtin_amdgcn_mfma_f32_16x16x32_bf16(Ar[0][dc], bb[kt],
                                                                     acc[0][kt], 0, 0, 0);
#pragma unroll
            for (int kt = 0; kt < 8; kt++)
                acc[1][kt] = __builtin_amdgcn_mfma_f32_16x16x32_bf16(Ar[1][dc], bb[kt],
                                                                     acc[1][kt], 0, 0, 0);
        }
        const int col = lane & 15;
#pragma unroll
        for (int kt = 0; kt < 8; kt++) {
            int k = (ktbase + kt) * 16 + col;
            float cn = cnorm[k];
#pragma unroll
            for (int nt = 0; nt < 2; nt++)
#pragma unroll
                for (int r = 0; r < 4; r++) {
                    float sc = fmaf(-2.0f, acc[nt][kt][r], cn);
                    if (sc < bestd[nt][r]) { bestd[nt][r] = sc; bestk[nt][r] = k; }
                }
        }
    }

    // reduce across the 16 columns, stash per-half result in LDS
#pragma unroll
    for (int nt = 0; nt < 2; nt++)
#pragma unroll
        for (int r = 0; r < 4; r++) {
            float dd = bestd[nt][r];
            int kk = bestk[nt][r];
#pragma unroll
            for (int off = 8; off >= 1; off >>= 1) {
                float d2 = __shfl_xor(dd, off);
                int k2 = __shfl_xor(kk, off);
                if (d2 < dd || (d2 == dd && k2 < kk)) { dd = d2; kk = k2; }
            }
            if ((lane & 15) == 0) {
                int nloc = (p * 2 + nt) * 16 + (lane >> 4) * 4 + r;
                sd[nloc][h] = dd;
                sk[nloc][h] = kk;
            }
        }
    __syncthreads();
    if (t < 128) {
        float d0 = sd[t][0], d1 = sd[t][1];
        int k0 = sk[t][0], k1 = sk[t][1];
        // half-0 codes always have smaller indices: strict < picks half 1
        int kk = (d1 < d0) ? k1 : k0;
        indices[blockIdx.x * 128 + t] = kk;
        atomicAdd(&counts[kk], 1);
    }
}

// ---------------------------------------------------------------------------
// Kernel D: quantize + STE output + loss, LDS-staged codebook rows.
// ---------------------------------------------------------------------------
__global__ __launch_bounds__(256) void quantize_loss(const float* __restrict__ z,
                                                     const float* __restrict__ cb,
                                                     const int* __restrict__ indices,
                                                     float* __restrict__ out,
                                                     float* __restrict__ lossacc) {
    __shared__ float qs[32 * 257];
    __shared__ float wsum[4];
    const int t = threadIdx.x;
    const int lane = t & 63;
    const int w = t >> 6;
    const int n0 = blockIdx.x * 32;
    const int b = n0 >> 10;
    const int hw0 = n0 & (HW - 1);

    {
        const int rsub = lane >> 4;  // 0..3
        const int f4b = lane & 15;   // 0..15
#pragma unroll
        for (int j = 0; j < 2; j++) {
            int r = (w * 2 + j) * 4 + rsub;  // 0..31
            int code = indices[n0 + r];
            const float4* src = (const float4*)(cb + (size_t)code * D_DIM);
#pragma unroll
            for (int k = 0; k < 4; k++) {
                int f4 = f4b + 16 * k;  // 0..63
                float4 v = src[f4];
                float* dst = &qs[r * 257 + f4 * 4];
                dst[0] = v.x;
                dst[1] = v.y;
                dst[2] = v.z;
                dst[3] = v.w;
            }
        }
    }
    __syncthreads();

    const int h = lane & 31;
    const int dhalf = lane >> 5;  // 0 or 1
    float ls = 0.f;
#pragma unroll 4
    for (int i = 0; i < 32; i++) {
        int d = (i * 4 + w) * 2 + dhalf;  // 0..255
        size_t o = (((size_t)(b * D_DIM + d)) << 10) + hw0 + h;
        float q = qs[h * 257 + d];
        float zv = z[o];
        float e = q - zv;
        out[o] = zv + e;
        ls = fmaf(e, e, ls);
    }
#pragma unroll
    for (int off = 32; off >= 1; off >>= 1) ls += __shfl_down(ls, off);
    if (lane == 0) wsum[w] = ls;
    __syncthreads();
    if (t == 0) atomicAdd(lossacc, wsum[0] + wsum[1] + wsum[2] + wsum[3]);
}

// ---------------------------------------------------------------------------
// Kernel E: write one-hot encodings (fused zero + scatter; 8B-aligned stores)
// ---------------------------------------------------------------------------
__global__ __launch_bounds__(256) void write_encodings(const int* __restrict__ indices,
                                                       float* __restrict__ enc) {
    int gid = blockIdx.x * 256 + threadIdx.x;  // 0..8388607, 4 floats each
    int n = gid >> 8;
    int k0 = (gid & 255) << 2;
    int idx = indices[n];
    float2 a, b2;
    a.x = (k0 == idx) ? 1.f : 0.f;
    a.y = (k0 + 1 == idx) ? 1.f : 0.f;
    b2.x = (k0 + 2 == idx) ? 1.f : 0.f;
    b2.y = (k0 + 3 == idx) ? 1.f : 0.f;
    float* p = enc + (size_t)gid * 4;
    *(float2*)p = a;
    *(float2*)(p + 2) = b2;
}

// ---------------------------------------------------------------------------
// Kernel F: finalize loss + perplexity
// ---------------------------------------------------------------------------
__global__ __launch_bounds__(256) void finalize_kernel(const int* __restrict__ counts,
                                                       const float* __restrict__ lossacc,
                                                       float* __restrict__ out_scalars) {
    int t = threadIdx.x;
    float s = 0.f;
#pragma unroll
    for (int i = 0; i < 4; i++) {
        int k = t + i * 256;
        float p = (float)counts[k] * (1.0f / 32768.0f);
        s += p * logf(p + 1e-10f);
    }
#pragma unroll
    for (int off = 32; off >= 1; off >>= 1) s += __shfl_down(s, off);
    __shared__ float red[4];
    if ((t & 63) == 0) red[t >> 6] = s;
    __syncthreads();
    if (t == 0) {
        float tot = red[0] + red[1] + red[2] + red[3];
        out_scalars[0] = 1.25f * (lossacc[0] * (1.0f / 8388608.0f));  // q + beta*e
        out_scalars[1] = expf(-tot);                                  // perplexity
    }
}

// ---------------------------------------------------------------------------
extern "C" void kernel_launch(void* const* d_in, const int* in_sizes, int n_in,
                              void* d_out, int out_size, void* d_ws, size_t ws_size,
                              hipStream_t stream) {
    const float* z = (const float*)d_in[0];   // [32,256,32,32]
    const float* cb = (const float*)d_in[1];  // [1024,256]
    float* out = (float*)d_out;
    char* wsb = (char*)d_ws;

    float* cnorm = (float*)wsb;             // 1024 f32
    int* counts = (int*)(wsb + 4096);       // 1024 i32
    float* lossacc = (float*)(wsb + 8192);  // 1 f32
    int* indices = (int*)(wsb + 16384);     // 32768 i32

    float* quant = out;             // [0, 8388608)
    float* scal = out + N_ELEM;     // loss @ +0, perplexity @ +1
    float* enc = out + N_ELEM + 2;  // [8388610, +33554432)

    // zb (16MB) + cbb (512KB) live inside the encodings region of d_out;
    // fully consumed by argmin_mfma before write_encodings overwrites them.
    unsigned short* zb = (unsigned short*)(out + 8388612);    // 16B-aligned
    unsigned short* cbb = (unsigned short*)(out + 12582916);  // 16B-aligned

    hipLaunchKernelGGL(cnorm_kernel, dim3(32), dim3(256), 0, stream, cb, cnorm,
                       counts, lossacc);
    hipLaunchKernelGGL(cbprep_kernel, dim3(128), dim3(256), 0, stream, cb, cbb);
    hipLaunchKernelGGL(zprep_kernel, dim3(4096), dim3(256), 0, stream, z, zb);
    hipLaunchKernelGGL(argmin_mfma, dim3(256), dim3(512), 0, stream, zb, cbb,
                       cnorm, indices, counts);
    hipLaunchKernelGGL(quantize_loss, dim3(1024), dim3(256), 0, stream, z, cb,
                       indices, quant, lossacc);
    hipLaunchKernelGGL(write_encodings, dim3(32768), dim3(256), 0, stream,
                       indices, enc);
    hipLaunchKernelGGL(finalize_kernel, dim3(1), dim3(256), 0, stream, counts,
                       lossacc, scal);
}

// Round 5
// 244.482 us; speedup vs baseline: 2.0818x; 1.1792x over previous
//
#include <hip/hip_runtime.h>
#include <hip/hip_bf16.h>

#define D_DIM 256
#define K_CODES 1024
#define HW 1024
#define N_VEC 32768
#define N_ELEM 8388608ull

typedef __attribute__((ext_vector_type(8))) short bf16x8;
typedef __attribute__((ext_vector_type(4))) float f32x4;

static __device__ __forceinline__ unsigned short f2bf(float x) {
    union { __hip_bfloat16 h; unsigned short u; } cvt;
    cvt.h = __float2bfloat16(x);
    return cvt.u;
}

// ---------------------------------------------------------------------------
// Kernel A (fused prep): codebook -> bf16 B-fragment order + codebook norms
// + zero counts/lossacc. 128 blocks x 256.
// ---------------------------------------------------------------------------
__global__ __launch_bounds__(256) void prep_kernel(const float* __restrict__ cb,
                                                   unsigned short* __restrict__ cbb,
                                                   float* __restrict__ cnorm,
                                                   int* __restrict__ counts,
                                                   float* __restrict__ lossacc) {
    int slot = blockIdx.x * 256 + threadIdx.x;  // 0 .. 32767
    // --- cbprep: fragment-order bf16 codebook ---
    {
        int lane = slot & 63;
        int dchunk = (slot >> 6) & 7;
        int ktile = slot >> 9;
        int code = ktile * 16 + (lane & 15);
        int d0 = dchunk * 32 + (lane >> 4) * 8;
        const float4* src = (const float4*)(cb + (size_t)code * D_DIM + d0);
        float4 v0 = src[0], v1 = src[1];
        int4 o;
        o.x = f2bf(v0.x) | ((unsigned)f2bf(v0.y) << 16);
        o.y = f2bf(v0.z) | ((unsigned)f2bf(v0.w) << 16);
        o.z = f2bf(v1.x) | ((unsigned)f2bf(v1.y) << 16);
        o.w = f2bf(v1.z) | ((unsigned)f2bf(v1.w) << 16);
        *(int4*)(cbb + (size_t)slot * 8) = o;
    }
    // --- cnorm (8 lanes per code) + zero counts/lossacc ---
    if (slot < 8192) {
        if (slot < K_CODES) counts[slot] = 0;
        if (slot == K_CODES) lossacc[0] = 0.f;
        int k = slot >> 3;
        int part = slot & 7;
        const float4* row = (const float4*)(cb + (size_t)k * D_DIM + part * 32);
        float s = 0.f;
#pragma unroll
        for (int i = 0; i < 8; i++) {
            float4 v = row[i];
            s = fmaf(v.x, v.x, s);
            s = fmaf(v.y, v.y, s);
            s = fmaf(v.z, v.z, s);
            s = fmaf(v.w, v.w, s);
        }
        s += __shfl_xor(s, 1);
        s += __shfl_xor(s, 2);
        s += __shfl_xor(s, 4);
        if (part == 0) cnorm[k] = s;
    }
}

// ---------------------------------------------------------------------------
// Kernel B: argmin via bf16 MFMA. Block = 256 thr (4 waves) = 128 n.
// A fragments converted in-register from z (fused zprep). B staged to LDS in
// fragment order via global_load_lds(16B), double-buffered 32KB chunks of
// 4 ktiles, ONE barrier per chunk (stage for c+1 issued right after the
// barrier => the pre-barrier vmcnt drain at c+1 is already satisfied).
// score = ||c||^2 - 2*z.c  (per-n ||z||^2 dropped; doesn't move argmin).
// ---------------------------------------------------------------------------
__global__ __launch_bounds__(256, 2) void argmin_mfma(const float* __restrict__ z,
                                                      const unsigned short* __restrict__ cbb,
                                                      const float* __restrict__ cnorm,
                                                      int* __restrict__ indices,
                                                      int* __restrict__ counts) {
    __shared__ unsigned short Bbuf[2][4 * 8 * 64 * 8];  // 2 x 32 KB
    const int t = threadIdx.x;
    const int lane = t & 63;
    const int w = t >> 6;                  // wave 0..3
    const int nt0 = blockIdx.x * 8 + w * 2;  // wave owns ntiles nt0, nt0+1

    // ---- prologue: load + convert A fragments (2 ntiles x 8 dchunks) ----
    bf16x8 Ar[2][8];
    {
        const int row = lane & 15;
        const int dq = (lane >> 4) * 8;
#pragma unroll
        for (int nt = 0; nt < 2; nt++) {
            int n = (nt0 + nt) * 16 + row;
            int b = n >> 10;
            int hw = n & (HW - 1);
#pragma unroll
            for (int dc = 0; dc < 8; dc++) {
                const float* src = z + (((size_t)(b * D_DIM + dc * 32 + dq)) << 10) + hw;
                union { bf16x8 v; unsigned short u[8]; } pk;
#pragma unroll
                for (int j = 0; j < 8; j++) pk.u[j] = f2bf(src[(size_t)j << 10]);
                Ar[nt][dc] = pk.v;
            }
        }
    }

    // ---- async stage of chunk 0 ----
    {
        const unsigned int* g = (const unsigned int*)cbb;
        unsigned int* l = (unsigned int*)Bbuf[0];
#pragma unroll
        for (int p = 0; p < 8; p++) {
            int off = (p * 256 + t) * 4;
            __builtin_amdgcn_global_load_lds(
                (const __attribute__((address_space(1))) unsigned int*)(g + off),
                (__attribute__((address_space(3))) unsigned int*)(l + off), 16, 0, 0);
        }
    }

    float bestd[2][4];
    int bestk[2][4];
#pragma unroll
    for (int nt = 0; nt < 2; nt++)
#pragma unroll
        for (int r = 0; r < 4; r++) { bestd[nt][r] = 3.4e38f; bestk[nt][r] = 0; }

    const int col = lane & 15;
    for (int c = 0; c < 16; c++) {
        const int cur = c & 1;
        __syncthreads();  // drains vmcnt -> Bbuf[cur] ready; all waves done with other buf
        if (c < 15) {
            const unsigned int* g = (const unsigned int*)(cbb + (size_t)(c + 1) * 16384);
            unsigned int* l = (unsigned int*)Bbuf[cur ^ 1];
#pragma unroll
            for (int p = 0; p < 8; p++) {
                int off = (p * 256 + t) * 4;
                __builtin_amdgcn_global_load_lds(
                    (const __attribute__((address_space(1))) unsigned int*)(g + off),
                    (__attribute__((address_space(3))) unsigned int*)(l + off), 16, 0, 0);
            }
        }
        const unsigned short* Bb = Bbuf[cur];
#pragma unroll
        for (int half = 0; half < 2; half++) {  // 2 ktiles at a time: 4 indep chains
            bf16x8 bb[2][8];
#pragma unroll
            for (int kt2 = 0; kt2 < 2; kt2++)
#pragma unroll
                for (int dc = 0; dc < 8; dc++)
                    bb[kt2][dc] = *(const bf16x8*)
                        &Bb[(((half * 2 + kt2) * 8 + dc) * 64 + lane) * 8];
            f32x4 acc[2][2];
#pragma unroll
            for (int nt = 0; nt < 2; nt++)
#pragma unroll
                for (int kt2 = 0; kt2 < 2; kt2++)
                    acc[nt][kt2] = (f32x4){0.f, 0.f, 0.f, 0.f};
#pragma unroll
            for (int dc = 0; dc < 8; dc++)
#pragma unroll
                for (int nt = 0; nt < 2; nt++)
#pragma unroll
                    for (int kt2 = 0; kt2 < 2; kt2++)
                        acc[nt][kt2] = __builtin_amdgcn_mfma_f32_16x16x32_bf16(
                            Ar[nt][dc], bb[kt2][dc], acc[nt][kt2], 0, 0, 0);
            // running best (k ascending => first-min tiebreak)
#pragma unroll
            for (int kt2 = 0; kt2 < 2; kt2++) {
                int k = (c * 4 + half * 2 + kt2) * 16 + col;
                float cn = cnorm[k];
#pragma unroll
                for (int nt = 0; nt < 2; nt++)
#pragma unroll
                    for (int r = 0; r < 4; r++) {
                        float sc = fmaf(-2.0f, acc[nt][kt2][r], cn);
                        if (sc < bestd[nt][r]) { bestd[nt][r] = sc; bestk[nt][r] = k; }
                    }
            }
        }
    }

    // ---- reduce across the 16 columns; full K per wave, no cross-wave step ----
#pragma unroll
    for (int nt = 0; nt < 2; nt++)
#pragma unroll
        for (int r = 0; r < 4; r++) {
            float dd = bestd[nt][r];
            int kk = bestk[nt][r];
#pragma unroll
            for (int off = 8; off >= 1; off >>= 1) {
                float d2 = __shfl_xor(dd, off);
                int k2 = __shfl_xor(kk, off);
                if (d2 < dd || (d2 == dd && k2 < kk)) { dd = d2; kk = k2; }
            }
            if ((lane & 15) == 0) {
                int n = (nt0 + nt) * 16 + (lane >> 4) * 4 + r;
                indices[n] = kk;
                atomicAdd(&counts[kk], 1);
            }
        }
}

// ---------------------------------------------------------------------------
// Kernel C: quantize + STE output + loss, LDS-staged codebook rows.
// ---------------------------------------------------------------------------
__global__ __launch_bounds__(256) void quantize_loss(const float* __restrict__ z,
                                                     const float* __restrict__ cb,
                                                     const int* __restrict__ indices,
                                                     float* __restrict__ out,
                                                     float* __restrict__ lossacc) {
    __shared__ float qs[32 * 257];
    __shared__ float wsum[4];
    const int t = threadIdx.x;
    const int lane = t & 63;
    const int w = t >> 6;
    const int n0 = blockIdx.x * 32;
    const int b = n0 >> 10;
    const int hw0 = n0 & (HW - 1);

    {
        const int rsub = lane >> 4;  // 0..3
        const int f4b = lane & 15;   // 0..15
#pragma unroll
        for (int j = 0; j < 2; j++) {
            int r = (w * 2 + j) * 4 + rsub;  // 0..31
            int code = indices[n0 + r];
            const float4* src = (const float4*)(cb + (size_t)code * D_DIM);
#pragma unroll
            for (int k = 0; k < 4; k++) {
                int f4 = f4b + 16 * k;  // 0..63
                float4 v = src[f4];
                float* dst = &qs[r * 257 + f4 * 4];
                dst[0] = v.x;
                dst[1] = v.y;
                dst[2] = v.z;
                dst[3] = v.w;
            }
        }
    }
    __syncthreads();

    const int h = lane & 31;
    const int dhalf = lane >> 5;  // 0 or 1
    float ls = 0.f;
#pragma unroll 4
    for (int i = 0; i < 32; i++) {
        int d = (i * 4 + w) * 2 + dhalf;  // 0..255
        size_t o = (((size_t)(b * D_DIM + d)) << 10) + hw0 + h;
        float q = qs[h * 257 + d];
        float zv = z[o];
        float e = q - zv;
        out[o] = zv + e;
        ls = fmaf(e, e, ls);
    }
#pragma unroll
    for (int off = 32; off >= 1; off >>= 1) ls += __shfl_down(ls, off);
    if (lane == 0) wsum[w] = ls;
    __syncthreads();
    if (t == 0) atomicAdd(lossacc, wsum[0] + wsum[1] + wsum[2] + wsum[3]);
}

// ---------------------------------------------------------------------------
// Kernel D: write one-hot encodings (fused zero + scatter; 8B-aligned stores)
// ---------------------------------------------------------------------------
__global__ __launch_bounds__(256) void write_encodings(const int* __restrict__ indices,
                                                       float* __restrict__ enc) {
    int gid = blockIdx.x * 256 + threadIdx.x;  // 0..8388607, 4 floats each
    int n = gid >> 8;
    int k0 = (gid & 255) << 2;
    int idx = indices[n];
    float2 a, b2;
    a.x = (k0 == idx) ? 1.f : 0.f;
    a.y = (k0 + 1 == idx) ? 1.f : 0.f;
    b2.x = (k0 + 2 == idx) ? 1.f : 0.f;
    b2.y = (k0 + 3 == idx) ? 1.f : 0.f;
    float* p = enc + (size_t)gid * 4;
    *(float2*)p = a;
    *(float2*)(p + 2) = b2;
}

// ---------------------------------------------------------------------------
// Kernel E: finalize loss + perplexity
// ---------------------------------------------------------------------------
__global__ __launch_bounds__(256) void finalize_kernel(const int* __restrict__ counts,
                                                       const float* __restrict__ lossacc,
                                                       float* __restrict__ out_scalars) {
    int t = threadIdx.x;
    float s = 0.f;
#pragma unroll
    for (int i = 0; i < 4; i++) {
        int k = t + i * 256;
        float p = (float)counts[k] * (1.0f / 32768.0f);
        s += p * logf(p + 1e-10f);
    }
#pragma unroll
    for (int off = 32; off >= 1; off >>= 1) s += __shfl_down(s, off);
    __shared__ float red[4];
    if ((t & 63) == 0) red[t >> 6] = s;
    __syncthreads();
    if (t == 0) {
        float tot = red[0] + red[1] + red[2] + red[3];
        out_scalars[0] = 1.25f * (lossacc[0] * (1.0f / 8388608.0f));  // q + beta*e
        out_scalars[1] = expf(-tot);                                  // perplexity
    }
}

// ---------------------------------------------------------------------------
extern "C" void kernel_launch(void* const* d_in, const int* in_sizes, int n_in,
                              void* d_out, int out_size, void* d_ws, size_t ws_size,
                              hipStream_t stream) {
    const float* z = (const float*)d_in[0];   // [32,256,32,32]
    const float* cb = (const float*)d_in[1];  // [1024,256]
    float* out = (float*)d_out;
    char* wsb = (char*)d_ws;

    float* cnorm = (float*)wsb;             // 1024 f32
    int* counts = (int*)(wsb + 4096);       // 1024 i32
    float* lossacc = (float*)(wsb + 8192);  // 1 f32
    int* indices = (int*)(wsb + 16384);     // 32768 i32

    float* quant = out;             // [0, 8388608)
    float* scal = out + N_ELEM;     // loss @ +0, perplexity @ +1
    float* enc = out + N_ELEM + 2;  // [8388610, +33554432)

    // cbb (512KB, bf16 fragment order) lives inside the encodings region of
    // d_out; fully consumed by argmin_mfma before write_encodings overwrites.
    unsigned short* cbb = (unsigned short*)(out + 8388612);  // 16B-aligned

    hipLaunchKernelGGL(prep_kernel, dim3(128), dim3(256), 0, stream, cb, cbb,
                       cnorm, counts, lossacc);
    hipLaunchKernelGGL(argmin_mfma, dim3(256), dim3(256), 0, stream, z, cbb,
                       cnorm, indices, counts);
    hipLaunchKernelGGL(quantize_loss, dim3(1024), dim3(256), 0, stream, z, cb,
                       indices, quant, lossacc);
    hipLaunchKernelGGL(write_encodings, dim3(32768), dim3(256), 0, stream,
                       indices, enc);
    hipLaunchKernelGGL(finalize_kernel, dim3(1), dim3(256), 0, stream, counts,
                       lossacc, scal);
}